// Round 5
// baseline (26.371 us; speedup 1.0000x reference)
//
#include <hip/hip_runtime.h>

// ClebschCombiningSingleUnrolledOld:
//   out[b,f,s] = sum_{m1+m2=s, m1,m2<9} X1[b,f,m1]*X2[b,f,m2]*CG[m1,m2]
// B=4096, F=256, L1=L2=9, lambd=4 -> out [B,F,9], all float32.
// Memory-bound: ~113 MB total traffic. Floor ~18 us @ 6.3 TB/s copy ceiling.
//
// R5 ablation: remove the OUTPUT LDS round-trip + second barrier.
// Each thread's 9 results already live at contiguous out[row*9..row*9+8];
// store them directly as 9 scalar dwords (36 B lane stride). L2 merges the
// temporally-adjacent partial lines; HBM write traffic unchanged.
// Input path unchanged: global->LDS DMA (width=16), one barrier.

constexpr int L = 9;                     // L1 == L2 == 2*lambd+1
constexpr int ROWS_PER_BLOCK = 256;
constexpr int FLOATS_PER_BLOCK = ROWS_PER_BLOCK * L;   // 2304
constexpr int VEC4_PER_BLOCK   = FLOATS_PER_BLOCK / 4; // 576

typedef __attribute__((address_space(3))) unsigned int       lds_u32;
typedef const __attribute__((address_space(1))) unsigned int glb_u32;

__device__ __forceinline__ void gload_lds16(const float* gsrc, float* ldsdst) {
    // 16-byte direct global->LDS DMA; LDS dest = wave-uniform base + lane*16.
    __builtin_amdgcn_global_load_lds((glb_u32*)gsrc, (lds_u32*)ldsdst, 16, 0, 0);
}

__global__ __launch_bounds__(256)
void cg_combine_kernel(const float* __restrict__ X1,
                       const float* __restrict__ X2,
                       const float* __restrict__ CG,
                       float* __restrict__ out,
                       long long total_floats)   // nrows * 9
{
    __shared__ float s1[FLOATS_PER_BLOCK];   // X1 slab
    __shared__ float s2[FLOATS_PER_BLOCK];   // X2 slab

    const int tid = threadIdx.x;
    const long long base = (long long)blockIdx.x * FLOATS_PER_BLOCK;
    const long long remaining = total_floats - base;   // >0 by grid construction
    const bool full = (remaining >= FLOATS_PER_BLOCK);

    // ---- staging: direct global -> LDS DMA (float4 granularity) ----
    if (full) {
        #pragma unroll
        for (int k = 0; k < 3; ++k) {
            const int i = tid + k * 256;           // float4 index in slab
            if (i < VEC4_PER_BLOCK) {              // whole waves active/inactive
                gload_lds16(X1 + base + (long long)i * 4, s1 + i * 4);
                gload_lds16(X2 + base + (long long)i * 4, s2 + i * 4);
            }
        }
    } else {
        for (int i = tid; i < FLOATS_PER_BLOCK; i += 256) {
            float a = 0.f, b = 0.f;
            if (i < remaining) { a = X1[base + i]; b = X2[base + i]; }
            s1[i] = a; s2[i] = b;
        }
    }
    __syncthreads();   // drains the DMA (vmcnt) before any LDS read

    // ---- per-thread row compute; direct scalar stores (no 2nd barrier) ----
    {
        float x1[L], x2[L];
        #pragma unroll
        for (int j = 0; j < L; ++j) {
            x1[j] = s1[tid * L + j];
            x2[j] = s2[tid * L + j];
        }
        float acc[L];
        #pragma unroll
        for (int s = 0; s < L; ++s) acc[s] = 0.f;

        #pragma unroll
        for (int m1 = 0; m1 < L; ++m1) {
            #pragma unroll
            for (int m2 = 0; m2 + m1 < L; ++m2) {
                // CG address is wave-uniform -> scalar s_load, cached
                acc[m1 + m2] = fmaf(x1[m1] * CG[m1 * L + m2], x2[m2], acc[m1 + m2]);
            }
        }

        const long long rowbase = base + (long long)tid * L;
        if (full) {
            #pragma unroll
            for (int s = 0; s < L; ++s) out[rowbase + s] = acc[s];
        } else {
            #pragma unroll
            for (int s = 0; s < L; ++s)
                if (rowbase + s < total_floats) out[rowbase + s] = acc[s];
        }
    }
}

extern "C" void kernel_launch(void* const* d_in, const int* in_sizes, int n_in,
                              void* d_out, int out_size, void* d_ws, size_t ws_size,
                              hipStream_t stream) {
    const float* X1 = (const float*)d_in[0];
    const float* X2 = (const float*)d_in[1];
    const float* CG = (const float*)d_in[2];
    float* out = (float*)d_out;

    const long long total_floats = (long long)in_sizes[0];  // B*F*9
    const int nblocks = (int)((total_floats + FLOATS_PER_BLOCK - 1) / FLOATS_PER_BLOCK);

    cg_combine_kernel<<<nblocks, 256, 0, stream>>>(X1, X2, CG, out, total_floats);
}

// Round 6
// 22.332 us; speedup vs baseline: 1.1809x; 1.1809x over previous
//
#include <hip/hip_runtime.h>

// ClebschCombiningSingleUnrolledOld:
//   out[b,f,s] = sum_{m1+m2=s, m1,m2<9} X1[b,f,m1]*X2[b,f,m2]*CG[m1,m2]
// B=4096, F=256, L1=L2=9, lambd=4 -> out [B,F,9], all float32.
// Memory-bound: ~113 MB total traffic; 22.2 us ~= 5.1 TB/s (81% of 6.3 TB/s
// copy ceiling). FINAL (R4 structure, best measured):
//  - global->LDS staging via __builtin_amdgcn_global_load_lds (width=16)
//  - per-thread 45-term CG triangle in registers (CG via scalar loads)
//  - output staged back through s1, coalesced nontemporal float4 stores
//    (R5 ablation proved direct scalar stores regress: 22.2 -> 26.4 us)
//  - LDS 18.4 KB -> 8 blocks/CU (full 32 waves/CU)

constexpr int L = 9;                     // L1 == L2 == 2*lambd+1
constexpr int ROWS_PER_BLOCK = 256;
constexpr int FLOATS_PER_BLOCK = ROWS_PER_BLOCK * L;   // 2304
constexpr int VEC4_PER_BLOCK   = FLOATS_PER_BLOCK / 4; // 576

typedef float __attribute__((ext_vector_type(4))) floatx4;   // native vector

typedef __attribute__((address_space(3))) unsigned int       lds_u32;
typedef const __attribute__((address_space(1))) unsigned int glb_u32;

__device__ __forceinline__ void gload_lds16(const float* gsrc, float* ldsdst) {
    // 16-byte direct global->LDS DMA; LDS dest = wave-uniform base + lane*16.
    __builtin_amdgcn_global_load_lds((glb_u32*)gsrc, (lds_u32*)ldsdst, 16, 0, 0);
}

__global__ __launch_bounds__(256)
void cg_combine_kernel(const float* __restrict__ X1,
                       const float* __restrict__ X2,
                       const float* __restrict__ CG,
                       float* __restrict__ out,
                       long long total_floats)   // nrows * 9
{
    __shared__ float s1[FLOATS_PER_BLOCK];   // X1 slab in, output slab out
    __shared__ float s2[FLOATS_PER_BLOCK];   // X2 slab

    const int tid = threadIdx.x;
    const long long base = (long long)blockIdx.x * FLOATS_PER_BLOCK;
    const long long remaining = total_floats - base;   // >0 by grid construction
    const bool full = (remaining >= FLOATS_PER_BLOCK);

    // ---- staging: direct global -> LDS DMA (float4 granularity) ----
    if (full) {
        #pragma unroll
        for (int k = 0; k < 3; ++k) {
            const int i = tid + k * 256;           // float4 index in slab
            if (i < VEC4_PER_BLOCK) {              // whole waves active/inactive
                gload_lds16(X1 + base + (long long)i * 4, s1 + i * 4);
                gload_lds16(X2 + base + (long long)i * 4, s2 + i * 4);
            }
        }
    } else {
        for (int i = tid; i < FLOATS_PER_BLOCK; i += 256) {
            float a = 0.f, b = 0.f;
            if (i < remaining) { a = X1[base + i]; b = X2[base + i]; }
            s1[i] = a; s2[i] = b;
        }
    }
    __syncthreads();   // drains the DMA (vmcnt) before any LDS read

    // ---- per-thread row compute; write result back over s1 (own slots) ----
    {
        float x1[L], x2[L];
        #pragma unroll
        for (int j = 0; j < L; ++j) {
            x1[j] = s1[tid * L + j];
            x2[j] = s2[tid * L + j];
        }
        float acc[L];
        #pragma unroll
        for (int s = 0; s < L; ++s) acc[s] = 0.f;

        #pragma unroll
        for (int m1 = 0; m1 < L; ++m1) {
            #pragma unroll
            for (int m2 = 0; m2 + m1 < L; ++m2) {
                // CG address is wave-uniform -> scalar s_load, cached
                acc[m1 + m2] = fmaf(x1[m1] * CG[m1 * L + m2], x2[m2], acc[m1 + m2]);
            }
        }
        #pragma unroll
        for (int s = 0; s < L; ++s) s1[tid * L + s] = acc[s];
    }
    __syncthreads();

    // ---- cooperative LDS -> global store (nontemporal float4) ----
    if (full) {
        floatx4* outv = reinterpret_cast<floatx4*>(out + base);
        const floatx4* sov = reinterpret_cast<const floatx4*>(s1);
        #pragma unroll
        for (int k = 0; k < 3; ++k) {
            const int i = tid + k * 256;
            if (i < VEC4_PER_BLOCK) {
                __builtin_nontemporal_store(sov[i], &outv[i]);
            }
        }
    } else {
        for (int i = tid; i < remaining; i += 256) out[base + i] = s1[i];
    }
}

extern "C" void kernel_launch(void* const* d_in, const int* in_sizes, int n_in,
                              void* d_out, int out_size, void* d_ws, size_t ws_size,
                              hipStream_t stream) {
    const float* X1 = (const float*)d_in[0];
    const float* X2 = (const float*)d_in[1];
    const float* CG = (const float*)d_in[2];
    float* out = (float*)d_out;

    const long long total_floats = (long long)in_sizes[0];  // B*F*9
    const int nblocks = (int)((total_floats + FLOATS_PER_BLOCK - 1) / FLOATS_PER_BLOCK);

    cg_combine_kernel<<<nblocks, 256, 0, stream>>>(X1, X2, CG, out, total_floats);
}